// Round 4
// baseline (236.405 us; speedup 1.0000x reference)
//
#include <hip/hip_runtime.h>
#include <hip/hip_bf16.h>

// Problem constants (B=2,S=2048 -> T=4096 tokens), H=1024, F=512, E=8, top-2.
#define T_TOK    4096
#define H_DIM    1024
#define F_DIM    512
#define N_EXP    8
#define N_ASSIGN 8192          // T_TOK * 2
#define BM 128
#define BN 128
#define BK 64
#define MAX_TILES 80
#define GRID_MT   71           // worst-case sum_e ceil(Ne/128) = 64 + 7

typedef __bf16 bf16x8 __attribute__((ext_vector_type(8)));
typedef float  f32x4  __attribute__((ext_vector_type(4)));

#define MFMA16(a, b, c) __builtin_amdgcn_mfma_f32_16x16x32_bf16((a), (b), (c), 0, 0, 0)

// Async global->LDS, 16B per lane. LDS dest = wave-uniform base + lane*16.
__device__ __forceinline__ void gl_lds16(const __bf16* g, __bf16* l) {
    __builtin_amdgcn_global_load_lds(
        (const __attribute__((address_space(1))) unsigned int*)g,
        (__attribute__((address_space(3))) unsigned int*)l,
        16, 0, 0);
}

// ---------------------------------------------------------------------------
// Routing: 1 wave = 1 token. Fuses x fp32->bf16 conversion. No global atomics
// (R2: clustered atomicAdds serialized 100us at the TCC).
// ---------------------------------------------------------------------------
__global__ __launch_bounds__(256) void routing_kernel(
    const float* __restrict__ x, const float* __restrict__ Wr,
    __bf16* __restrict__ xb, int* __restrict__ top_e, float* __restrict__ top_w)
{
    int wave = threadIdx.x >> 6, lane = threadIdx.x & 63;
    int t = blockIdx.x * 4 + wave;
    const float* xrow = x + (size_t)t * H_DIM;
    __bf16* xbrow = xb + (size_t)t * H_DIM;

    float part[N_EXP];
#pragma unroll
    for (int e = 0; e < N_EXP; ++e) part[e] = 0.f;

#pragma unroll
    for (int half = 0; half < 2; ++half) {
        int h0 = half * 512 + lane * 8;
        float4 v0 = *(const float4*)(xrow + h0);
        float4 v1 = *(const float4*)(xrow + h0 + 4);
        float xs[8] = {v0.x, v0.y, v0.z, v0.w, v1.x, v1.y, v1.z, v1.w};
        bf16x8 bv;
#pragma unroll
        for (int i = 0; i < 8; ++i) bv[i] = (__bf16)xs[i];
        *(bf16x8*)(xbrow + h0) = bv;
#pragma unroll
        for (int i = 0; i < 8; ++i) {
            const float4* wr = (const float4*)(Wr + (size_t)(h0 + i) * N_EXP);
            float4 w0 = wr[0], w1 = wr[1];
            part[0] += xs[i] * w0.x; part[1] += xs[i] * w0.y;
            part[2] += xs[i] * w0.z; part[3] += xs[i] * w0.w;
            part[4] += xs[i] * w1.x; part[5] += xs[i] * w1.y;
            part[6] += xs[i] * w1.z; part[7] += xs[i] * w1.w;
        }
    }
#pragma unroll
    for (int m = 1; m < 64; m <<= 1) {
#pragma unroll
        for (int e = 0; e < N_EXP; ++e) part[e] += __shfl_xor(part[e], m, 64);
    }
    if (lane == 0) {
        float v1 = -1e30f, v2 = -1e30f;
        int i1 = 0, i2 = 0;
#pragma unroll
        for (int e = 0; e < N_EXP; ++e) {
            float p = part[e];
            if (p > v1)      { v2 = v1; i2 = i1; v1 = p; i1 = e; }
            else if (p > v2) { v2 = p;  i2 = e; }
        }
        float w1 = 1.f / (1.f + __expf(v2 - v1));
        top_e[t * 2]     = i1;  top_e[t * 2 + 1] = i2;
        top_w[t * 2]     = w1;  top_w[t * 2 + 1] = 1.f - w1;
    }
}

// ---------------------------------------------------------------------------
// Single-block deterministic counting sort (no atomics). Emits 128-row tiles.
// ---------------------------------------------------------------------------
__global__ __launch_bounds__(256) void schedule_scatter(
    const int* __restrict__ top_e, const float* __restrict__ top_w,
    int* __restrict__ perm, float* __restrict__ wts,
    int* __restrict__ tile_e, int* __restrict__ tile_m0, int* __restrict__ tile_cnt,
    int* __restrict__ n_tiles)
{
    __shared__ int hist[N_EXP][256];
    __shared__ int ebase[N_EXP];
    int tid = threadIdx.x;

    int c[N_EXP];
#pragma unroll
    for (int e = 0; e < N_EXP; ++e) c[e] = 0;
#pragma unroll 4
    for (int i = 0; i < 32; ++i) {
        int ee = top_e[tid * 32 + i];
#pragma unroll
        for (int e = 0; e < N_EXP; ++e) c[e] += (ee == e);
    }
#pragma unroll
    for (int e = 0; e < N_EXP; ++e) hist[e][tid] = c[e];
    __syncthreads();

    for (int s = 1; s < 256; s <<= 1) {
        int v[N_EXP];
#pragma unroll
        for (int e = 0; e < N_EXP; ++e) v[e] = (tid >= s) ? hist[e][tid - s] : 0;
        __syncthreads();
#pragma unroll
        for (int e = 0; e < N_EXP; ++e) hist[e][tid] += v[e];
        __syncthreads();
    }

    if (tid == 0) {
        int o = 0, nt = 0;
        for (int e = 0; e < N_EXP; ++e) {
            ebase[e] = o;
            int ne = hist[e][255];
            for (int m0 = 0; m0 < ne; m0 += BM) {
                tile_e[nt]   = e;
                tile_m0[nt]  = o + m0;
                tile_cnt[nt] = (ne - m0 < BM) ? (ne - m0) : BM;
                ++nt;
            }
            o += ne;
        }
        *n_tiles = nt;
    }
    __syncthreads();

#pragma unroll
    for (int e = 0; e < N_EXP; ++e) hist[e][tid] = ebase[e] + hist[e][tid] - c[e];
#pragma unroll 4
    for (int i = 0; i < 32; ++i) {
        int a = tid * 32 + i;
        int e = top_e[a];
        int slot = hist[e][tid]++;
        perm[slot] = a >> 1;
        wts[slot]  = top_w[a];
    }
}

// ---------------------------------------------------------------------------
// fp32 -> bf16 + transpose to K(=src row)-contiguous layouts.
//   z<8 : Wg[h][f] -> Wcat[e][p_g(f)][h]    p_g(f) = (f>>4)*32 + (f&15)
//   z<16: Wu[h][f] -> Wcat[e][p_u(f)][h]    p_u(f) = p_g(f) + 16
//   else: Wd[f][h] -> Wdt [e][h][f]
// Packed Wcat: 16-col gate / 16-col up interleave so one GEMM wave holds
// matching gate/up accumulators for the SwiGLU epilogue.
// ---------------------------------------------------------------------------
__global__ __launch_bounds__(256) void transpose_kernel(
    const float* __restrict__ Wg, const float* __restrict__ Wu, const float* __restrict__ Wd,
    __bf16* __restrict__ Wcat, __bf16* __restrict__ Wdt)
{
    int z = blockIdx.z;
    const float* src; int R, C;
    if (z < 8)       { src = Wg + (size_t)z * H_DIM * F_DIM;        R = H_DIM; C = F_DIM; }
    else if (z < 16) { src = Wu + (size_t)(z - 8) * H_DIM * F_DIM;  R = H_DIM; C = F_DIM; }
    else             { src = Wd + (size_t)(z - 16) * F_DIM * H_DIM; R = F_DIM; C = H_DIM; }
    int c0 = blockIdx.x * 32, r0 = blockIdx.y * 32;
    if (c0 >= C || r0 >= R) return;
    __shared__ float tile[32][33];
    int tx = threadIdx.x & 31, ty = threadIdx.x >> 5;
#pragma unroll
    for (int i = 0; i < 4; ++i)
        tile[ty + 8 * i][tx] = src[(size_t)(r0 + ty + 8 * i) * C + c0 + tx];
    __syncthreads();
    if (z < 16) {
        int e = (z < 8) ? z : z - 8;
        __bf16* dst = Wcat + (size_t)e * (2 * F_DIM) * H_DIM;
#pragma unroll
        for (int i = 0; i < 4; ++i) {
            int f = c0 + ty + 8 * i;
            int p = ((f >> 4) << 5) + (f & 15) + ((z < 8) ? 0 : 16);
            dst[(size_t)p * H_DIM + r0 + tx] = (__bf16)tile[tx][ty + 8 * i];
        }
    } else {
        __bf16* dst = Wdt + (size_t)(z - 16) * H_DIM * F_DIM;
#pragma unroll
        for (int i = 0; i < 4; ++i)
            dst[(size_t)(c0 + ty + 8 * i) * F_DIM + r0 + tx] = (__bf16)tile[tx][ty + 8 * i];
    }
}

// ---------------------------------------------------------------------------
// m97-structure grouped GEMM for gate+up (packed N=1024), 128x128 tile, BK=64,
// global_load_lds width-16 staging, XOR-swizzled LDS (LDS[r][c] = G[r][c^(r&7)]
// in 8-elem chunks; swizzle applied to the per-lane GLOBAL address, so the
// wave-uniform-base+lane*16 LDS constraint is satisfied with zero padding).
// Epilogue: silu(gate)*up*combine_weight -> act (bf16).
// ---------------------------------------------------------------------------
__global__ __launch_bounds__(256, 3) void gateup_kernel(
    const __bf16* __restrict__ xb, const __bf16* __restrict__ Wcat,
    const int* __restrict__ perm, const float* __restrict__ wts,
    const int* __restrict__ tile_e, const int* __restrict__ tile_m0, const int* __restrict__ tile_cnt,
    const int* __restrict__ n_tiles, __bf16* __restrict__ act)
{
    if ((int)blockIdx.x >= *n_tiles) return;
    int e = tile_e[blockIdx.x], m0 = tile_m0[blockIdx.x], mcnt = tile_cnt[blockIdx.x];
    int n0 = blockIdx.y * BN;                       // packed col base

    __shared__ __align__(16) __bf16 As[BM * BK];    // 16 KB, row=64 elems=128B
    __shared__ __align__(16) __bf16 Bs[BN * BK];    // 16 KB
    __shared__ int   rowtok[BM];
    __shared__ float roww[BM];

    int tid = threadIdx.x;
    if (tid < BM) {
        int slot = m0 + ((tid < mcnt) ? tid : 0);
        rowtok[tid] = perm[slot];
        roww[tid]   = wts[slot];
    }
    __syncthreads();

    int wave = tid >> 6, lane = tid & 63;
    // staging: instr j covers rows j*32 + wave*8 + (lane>>3); global chunk XOR-swizzled
    int srow   = wave * 8 + (lane >> 3);
    int schunk = (((lane & 7) ^ ((lane >> 3) & 7))) * 8;   // element offset in [0,64)
    const __bf16* We = Wcat + (size_t)e * (2 * F_DIM) * H_DIM;
    const __bf16* aptr[4];
    const __bf16* bptr[4];
#pragma unroll
    for (int j = 0; j < 4; ++j) {
        int r = j * 32 + srow;
        aptr[j] = xb + (size_t)rowtok[r] * H_DIM + schunk;
        bptr[j] = We + (size_t)(n0 + r) * H_DIM + schunk;
    }
    __bf16* aLds = As + wave * 512;     // wave-uniform; lane*16B implicit
    __bf16* bLds = Bs + wave * 512;

    int wm = wave & 1, wn = wave >> 1;
    int quad = lane >> 4, l16 = lane & 15;

    f32x4 acc[4][4];
#pragma unroll
    for (int a = 0; a < 4; ++a)
#pragma unroll
        for (int b = 0; b < 4; ++b) acc[a][b] = (f32x4){0.f, 0.f, 0.f, 0.f};

    for (int k0 = 0; k0 < H_DIM; k0 += BK) {
#pragma unroll
        for (int j = 0; j < 4; ++j) {
            gl_lds16(aptr[j] + k0, aLds + j * 2048);
            gl_lds16(bptr[j] + k0, bLds + j * 2048);
        }
        __syncthreads();
#pragma unroll
        for (int s = 0; s < 2; ++s) {
            int sw = (((quad + s * 4) ^ (l16 & 7))) * 8;
            bf16x8 af[4], bf[4];
#pragma unroll
            for (int im = 0; im < 4; ++im)
                af[im] = *(const bf16x8*)&As[(wm * 64 + im * 16 + l16) * 64 + sw];
#pragma unroll
            for (int in = 0; in < 4; ++in)
                bf[in] = *(const bf16x8*)&Bs[(wn * 64 + in * 16 + l16) * 64 + sw];
#pragma unroll
            for (int im = 0; im < 4; ++im)
#pragma unroll
                for (int in = 0; in < 4; ++in)
                    acc[im][in] = MFMA16(af[im], bf[in], acc[im][in]);
        }
        __syncthreads();
    }

    // Epilogue: packed col P = n0 + wn*64 + in*16 + l16; in even=gate, odd=up
    // (same f range for the pair). f = n0/2 + wn*32 + (in>>1)*16 + l16.
    int fbase = (n0 >> 1) + wn * 32;
#pragma unroll
    for (int im = 0; im < 4; ++im) {
#pragma unroll
        for (int ip = 0; ip < 2; ++ip) {
            f32x4 g = acc[im][ip * 2], u = acc[im][ip * 2 + 1];
            int fcol = fbase + ip * 16 + l16;
#pragma unroll
            for (int r = 0; r < 4; ++r) {
                int rl = wm * 64 + im * 16 + quad * 4 + r;
                if (rl < mcnt) {
                    float gv = g[r], uv = u[r];
                    float sg = gv / (1.f + __expf(-gv));
                    act[(size_t)(m0 + rl) * F_DIM + fcol] = (__bf16)(sg * uv * roww[rl]);
                }
            }
        }
    }
}

// ---------------------------------------------------------------------------
// m97-structure grouped down-proj: out[token][h] += act_slot @ Wd[e].
// Same staging/swizzle; epilogue fp32 native atomics (<=2 writers/address).
// ---------------------------------------------------------------------------
__global__ __launch_bounds__(256, 3) void down_kernel(
    const __bf16* __restrict__ act, const __bf16* __restrict__ Wdt,
    const int* __restrict__ perm,
    const int* __restrict__ tile_e, const int* __restrict__ tile_m0, const int* __restrict__ tile_cnt,
    const int* __restrict__ n_tiles, float* __restrict__ out)
{
    if ((int)blockIdx.x >= *n_tiles) return;
    int e = tile_e[blockIdx.x], m0 = tile_m0[blockIdx.x], mcnt = tile_cnt[blockIdx.x];
    int n0 = blockIdx.y * BN;

    __shared__ __align__(16) __bf16 As[BM * BK];
    __shared__ __align__(16) __bf16 Bs[BN * BK];
    __shared__ int rowtok[BM];

    int tid = threadIdx.x;
    if (tid < BM) rowtok[tid] = perm[m0 + ((tid < mcnt) ? tid : 0)];
    __syncthreads();

    int wave = tid >> 6, lane = tid & 63;
    int srow   = wave * 8 + (lane >> 3);
    int schunk = (((lane & 7) ^ ((lane >> 3) & 7))) * 8;
    const __bf16* Wd_e = Wdt + (size_t)e * H_DIM * F_DIM;
    const __bf16* aptr[4];
    const __bf16* bptr[4];
#pragma unroll
    for (int j = 0; j < 4; ++j) {
        int r = j * 32 + srow;
        int ar = m0 + ((r < mcnt) ? r : 0);
        aptr[j] = act  + (size_t)ar * F_DIM + schunk;
        bptr[j] = Wd_e + (size_t)(n0 + r) * F_DIM + schunk;
    }
    __bf16* aLds = As + wave * 512;
    __bf16* bLds = Bs + wave * 512;

    int wm = wave & 1, wn = wave >> 1;
    int quad = lane >> 4, l16 = lane & 15;

    f32x4 acc[4][4];
#pragma unroll
    for (int a = 0; a < 4; ++a)
#pragma unroll
        for (int b = 0; b < 4; ++b) acc[a][b] = (f32x4){0.f, 0.f, 0.f, 0.f};

    for (int k0 = 0; k0 < F_DIM; k0 += BK) {
#pragma unroll
        for (int j = 0; j < 4; ++j) {
            gl_lds16(aptr[j] + k0, aLds + j * 2048);
            gl_lds16(bptr[j] + k0, bLds + j * 2048);
        }
        __syncthreads();
#pragma unroll
        for (int s = 0; s < 2; ++s) {
            int sw = (((quad + s * 4) ^ (l16 & 7))) * 8;
            bf16x8 af[4], bf[4];
#pragma unroll
            for (int im = 0; im < 4; ++im)
                af[im] = *(const bf16x8*)&As[(wm * 64 + im * 16 + l16) * 64 + sw];
#pragma unroll
            for (int in = 0; in < 4; ++in)
                bf[in] = *(const bf16x8*)&Bs[(wn * 64 + in * 16 + l16) * 64 + sw];
#pragma unroll
            for (int im = 0; im < 4; ++im)
#pragma unroll
                for (int in = 0; in < 4; ++in)
                    acc[im][in] = MFMA16(af[im], bf[in], acc[im][in]);
        }
        __syncthreads();
    }

#pragma unroll
    for (int im = 0; im < 4; ++im) {
#pragma unroll
        for (int in = 0; in < 4; ++in) {
            int col = n0 + wn * 64 + in * 16 + l16;
#pragma unroll
            for (int r = 0; r < 4; ++r) {
                int rl = wm * 64 + im * 16 + quad * 4 + r;
                if (rl < mcnt)
                    unsafeAtomicAdd(out + (size_t)rowtok[rl] * H_DIM + col, acc[im][in][r]);
            }
        }
    }
}

// ---------------------------------------------------------------------------
extern "C" void kernel_launch(void* const* d_in, const int* in_sizes, int n_in,
                              void* d_out, int out_size, void* d_ws, size_t ws_size,
                              hipStream_t stream)
{
    const float* x  = (const float*)d_in[0];
    const float* Wr = (const float*)d_in[1];
    const float* Wg = (const float*)d_in[2];
    const float* Wu = (const float*)d_in[3];
    const float* Wd = (const float*)d_in[4];
    float* out = (float*)d_out;

    char* ws = (char*)d_ws;
    size_t off = 0;
    auto carve = [&](size_t bytes) {
        char* p = ws + off;
        off = (off + bytes + 255) & ~(size_t)255;
        return p;
    };
    __bf16* xb   = (__bf16*)carve((size_t)T_TOK * H_DIM * 2);                 // 8 MB
    __bf16* Wcat = (__bf16*)carve((size_t)N_EXP * 2 * F_DIM * H_DIM * 2);     // 16 MB
    __bf16* Wdt  = (__bf16*)carve((size_t)N_EXP * H_DIM * F_DIM * 2);         // 8 MB
    __bf16* act  = (__bf16*)carve((size_t)N_ASSIGN * F_DIM * 2);              // 8 MB
    int*   top_e = (int*)carve((size_t)T_TOK * 2 * sizeof(int));
    float* top_w = (float*)carve((size_t)T_TOK * 2 * sizeof(float));
    int*   perm  = (int*)carve((size_t)N_ASSIGN * sizeof(int));
    float* wts   = (float*)carve((size_t)N_ASSIGN * sizeof(float));
    int*   tl_e  = (int*)carve(MAX_TILES * sizeof(int));
    int*   tl_m0 = (int*)carve(MAX_TILES * sizeof(int));
    int*   tl_cn = (int*)carve(MAX_TILES * sizeof(int));
    int*   n_til = (int*)carve(sizeof(int));

    hipMemsetAsync(d_out, 0, (size_t)out_size * sizeof(float), stream);

    routing_kernel<<<T_TOK / 4, 256, 0, stream>>>(x, Wr, xb, top_e, top_w);
    schedule_scatter<<<1, 256, 0, stream>>>(top_e, top_w, perm, wts,
                                            tl_e, tl_m0, tl_cn, n_til);
    transpose_kernel<<<dim3(32, 32, 24), 256, 0, stream>>>(Wg, Wu, Wd, Wcat, Wdt);
    gateup_kernel<<<dim3(GRID_MT, (2 * F_DIM) / BN), 256, 0, stream>>>(
        xb, Wcat, perm, wts, tl_e, tl_m0, tl_cn, n_til, act);
    down_kernel<<<dim3(GRID_MT, H_DIM / BN), 256, 0, stream>>>(
        act, Wdt, perm, tl_e, tl_m0, tl_cn, n_til, out);
}

// Round 5
// 221.204 us; speedup vs baseline: 1.0687x; 1.0687x over previous
//
#include <hip/hip_runtime.h>
#include <hip/hip_bf16.h>

// Problem constants (B=2,S=2048 -> T=4096 tokens), H=1024, F=512, E=8, top-2.
#define T_TOK    4096
#define H_DIM    1024
#define F_DIM    512
#define N_EXP    8
#define N_ASSIGN 8192          // T_TOK * 2
#define BM 128
#define BN 128
#define BK 64
#define MAX_TILES 80
#define GRID_MT   71           // worst-case sum_e ceil(Ne/128) = 64 + 7

typedef __bf16 bf16x8 __attribute__((ext_vector_type(8)));
typedef __bf16 bf16x2 __attribute__((ext_vector_type(2)));
typedef float  f32x4  __attribute__((ext_vector_type(4)));

#define MFMA16(a, b, c) __builtin_amdgcn_mfma_f32_16x16x32_bf16((a), (b), (c), 0, 0, 0)

// Async global->LDS, 16B per lane. LDS dest = wave-uniform base + lane*16.
__device__ __forceinline__ void gl_lds16(const __bf16* g, __bf16* l) {
    __builtin_amdgcn_global_load_lds(
        (const __attribute__((address_space(1))) unsigned int*)g,
        (__attribute__((address_space(3))) unsigned int*)l,
        16, 0, 0);
}

// ---------------------------------------------------------------------------
// Routing: 1 wave = 1 token. Fuses x fp32->bf16 conversion. No global atomics
// (R2: clustered atomicAdds serialized 100us at the TCC).
// ---------------------------------------------------------------------------
__global__ __launch_bounds__(256) void routing_kernel(
    const float* __restrict__ x, const float* __restrict__ Wr,
    __bf16* __restrict__ xb, int* __restrict__ top_e, float* __restrict__ top_w)
{
    int wave = threadIdx.x >> 6, lane = threadIdx.x & 63;
    int t = blockIdx.x * 4 + wave;
    const float* xrow = x + (size_t)t * H_DIM;
    __bf16* xbrow = xb + (size_t)t * H_DIM;

    float part[N_EXP];
#pragma unroll
    for (int e = 0; e < N_EXP; ++e) part[e] = 0.f;

#pragma unroll
    for (int half = 0; half < 2; ++half) {
        int h0 = half * 512 + lane * 8;
        float4 v0 = *(const float4*)(xrow + h0);
        float4 v1 = *(const float4*)(xrow + h0 + 4);
        float xs[8] = {v0.x, v0.y, v0.z, v0.w, v1.x, v1.y, v1.z, v1.w};
        bf16x8 bv;
#pragma unroll
        for (int i = 0; i < 8; ++i) bv[i] = (__bf16)xs[i];
        *(bf16x8*)(xbrow + h0) = bv;
#pragma unroll
        for (int i = 0; i < 8; ++i) {
            const float4* wr = (const float4*)(Wr + (size_t)(h0 + i) * N_EXP);
            float4 w0 = wr[0], w1 = wr[1];
            part[0] += xs[i] * w0.x; part[1] += xs[i] * w0.y;
            part[2] += xs[i] * w0.z; part[3] += xs[i] * w0.w;
            part[4] += xs[i] * w1.x; part[5] += xs[i] * w1.y;
            part[6] += xs[i] * w1.z; part[7] += xs[i] * w1.w;
        }
    }
#pragma unroll
    for (int m = 1; m < 64; m <<= 1) {
#pragma unroll
        for (int e = 0; e < N_EXP; ++e) part[e] += __shfl_xor(part[e], m, 64);
    }
    if (lane == 0) {
        float v1 = -1e30f, v2 = -1e30f;
        int i1 = 0, i2 = 0;
#pragma unroll
        for (int e = 0; e < N_EXP; ++e) {
            float p = part[e];
            if (p > v1)      { v2 = v1; i2 = i1; v1 = p; i1 = e; }
            else if (p > v2) { v2 = p;  i2 = e; }
        }
        float w1 = 1.f / (1.f + __expf(v2 - v1));
        top_e[t * 2]     = i1;  top_e[t * 2 + 1] = i2;
        top_w[t * 2]     = w1;  top_w[t * 2 + 1] = 1.f - w1;
    }
}

// ---------------------------------------------------------------------------
// Scan kernel (1 block): histogram + Hillis-Steele scan -> tile worklist +
// per-(thread,expert) scatter bases. NO scattered stores here (they were the
// single-CU bottleneck) -- scatter runs in the 8-block kernel below.
// ---------------------------------------------------------------------------
__global__ __launch_bounds__(256) void scan_kernel(
    const int* __restrict__ top_e,
    int* __restrict__ tile_e, int* __restrict__ tile_m0, int* __restrict__ tile_cnt,
    int* __restrict__ n_tiles, int* __restrict__ tbase)   // tbase[8][256]
{
    __shared__ int hist[N_EXP][256];
    __shared__ int ebase[N_EXP];
    int tid = threadIdx.x;

    int c[N_EXP];
#pragma unroll
    for (int e = 0; e < N_EXP; ++e) c[e] = 0;
#pragma unroll 4
    for (int i = 0; i < 32; ++i) {
        int ee = top_e[tid * 32 + i];
#pragma unroll
        for (int e = 0; e < N_EXP; ++e) c[e] += (ee == e);
    }
#pragma unroll
    for (int e = 0; e < N_EXP; ++e) hist[e][tid] = c[e];
    __syncthreads();

    for (int s = 1; s < 256; s <<= 1) {
        int v[N_EXP];
#pragma unroll
        for (int e = 0; e < N_EXP; ++e) v[e] = (tid >= s) ? hist[e][tid - s] : 0;
        __syncthreads();
#pragma unroll
        for (int e = 0; e < N_EXP; ++e) hist[e][tid] += v[e];
        __syncthreads();
    }

    if (tid == 0) {
        int o = 0, nt = 0;
        for (int e = 0; e < N_EXP; ++e) {
            ebase[e] = o;
            int ne = hist[e][255];
            for (int m0 = 0; m0 < ne; m0 += BM) {
                tile_e[nt]   = e;
                tile_m0[nt]  = o + m0;
                tile_cnt[nt] = (ne - m0 < BM) ? (ne - m0) : BM;
                ++nt;
            }
            o += ne;
        }
        *n_tiles = nt;
    }
    __syncthreads();

#pragma unroll
    for (int e = 0; e < N_EXP; ++e)
        tbase[e * 256 + tid] = ebase[e] + hist[e][tid] - c[e];
}

// ---------------------------------------------------------------------------
// Scatter kernel: one block per expert. Thread tid walks slot tid's 32
// assignments in order, emitting only expert blockIdx.x at its precomputed
// base -- deterministic, no atomics, 8 CUs issuing stores instead of 1.
// ---------------------------------------------------------------------------
__global__ __launch_bounds__(256) void scatter_kernel(
    const int* __restrict__ top_e, const float* __restrict__ top_w,
    const int* __restrict__ tbase,
    int* __restrict__ perm, float* __restrict__ wts)
{
    int e = blockIdx.x, tid = threadIdx.x;
    int base = tbase[e * 256 + tid];
#pragma unroll 4
    for (int i = 0; i < 32; ++i) {
        int a = tid * 32 + i;
        if (top_e[a] == e) {
            perm[base] = a >> 1;
            wts[base]  = top_w[a];
            ++base;
        }
    }
}

// ---------------------------------------------------------------------------
// fp32 -> bf16 + transpose to K(=src row)-contiguous layouts. 64r x 32c tile,
// 4-byte bf16x2 stores (R4 version used 2-byte scalar stores).
//   z<8 : Wg[h][f] -> Wcat[e][p_g(f)][h]    p_g(f) = (f>>4)*32 + (f&15)
//   z<16: Wu[h][f] -> Wcat[e][p_u(f)][h]    p_u(f) = p_g(f) + 16
//   else: Wd[f][h] -> Wdt [e][h][f]
// ---------------------------------------------------------------------------
__global__ __launch_bounds__(256) void transpose_kernel(
    const float* __restrict__ Wg, const float* __restrict__ Wu, const float* __restrict__ Wd,
    __bf16* __restrict__ Wcat, __bf16* __restrict__ Wdt)
{
    int z = blockIdx.z;
    const float* src; int R, C;
    if (z < 8)       { src = Wg + (size_t)z * H_DIM * F_DIM;        R = H_DIM; C = F_DIM; }
    else if (z < 16) { src = Wu + (size_t)(z - 8) * H_DIM * F_DIM;  R = H_DIM; C = F_DIM; }
    else             { src = Wd + (size_t)(z - 16) * F_DIM * H_DIM; R = F_DIM; C = H_DIM; }
    int c0 = blockIdx.x * 32, r0 = blockIdx.y * 64;
    if (c0 >= C || r0 >= R) return;
    __shared__ float tile[64][33];
    int tx = threadIdx.x & 31, ty = threadIdx.x >> 5;    // 32 x 8
#pragma unroll
    for (int i = 0; i < 8; ++i)                          // 64 rows
        tile[ty + 8 * i][tx] = src[(size_t)(r0 + ty + 8 * i) * C + c0 + tx];
    __syncthreads();
    // store: thread covers col c = c0+ty+8i (i<4), rows r0+2tx, r0+2tx+1
    if (z < 16) {
        int e = (z < 8) ? z : z - 8;
        int sel = (z < 8) ? 0 : 16;
        __bf16* dst = Wcat + (size_t)e * (2 * F_DIM) * H_DIM;
#pragma unroll
        for (int i = 0; i < 4; ++i) {
            int f = c0 + ty + 8 * i;
            int p = ((f >> 4) << 5) + (f & 15) + sel;
            bf16x2 v = { (__bf16)tile[2 * tx][ty + 8 * i], (__bf16)tile[2 * tx + 1][ty + 8 * i] };
            *(bf16x2*)&dst[(size_t)p * H_DIM + r0 + 2 * tx] = v;
        }
    } else {
        __bf16* dst = Wdt + (size_t)(z - 16) * H_DIM * F_DIM;
#pragma unroll
        for (int i = 0; i < 4; ++i) {
            bf16x2 v = { (__bf16)tile[2 * tx][ty + 8 * i], (__bf16)tile[2 * tx + 1][ty + 8 * i] };
            *(bf16x2*)&dst[(size_t)(c0 + ty + 8 * i) * F_DIM + r0 + 2 * tx] = v;
        }
    }
}

// ---------------------------------------------------------------------------
// m97-structure grouped GEMM for gate+up (packed N=1024), 128x128 tile, BK=64,
// global_load_lds width-16 staging, XOR-swizzled LDS. 1-D grid, n-FASTEST
// decode: adjacent 8 blocks share the A-tile (L3/L2 reuse); stride-8 blocks
// share the B-tile AND the XCD (8-XCD round-robin) -> per-XCD L2 B hits.
// Epilogue: silu(gate)*up*combine_weight -> act (bf16).
// ---------------------------------------------------------------------------
__global__ __launch_bounds__(256, 3) void gateup_kernel(
    const __bf16* __restrict__ xb, const __bf16* __restrict__ Wcat,
    const int* __restrict__ perm, const float* __restrict__ wts,
    const int* __restrict__ tile_e, const int* __restrict__ tile_m0, const int* __restrict__ tile_cnt,
    const int* __restrict__ n_tiles, __bf16* __restrict__ act)
{
    int mt = blockIdx.x >> 3;               // n varies fastest
    if (mt >= *n_tiles) return;
    int e = tile_e[mt], m0 = tile_m0[mt], mcnt = tile_cnt[mt];
    int n0 = (blockIdx.x & 7) * BN;         // packed col base

    __shared__ __align__(16) __bf16 As[BM * BK];    // 16 KB
    __shared__ __align__(16) __bf16 Bs[BN * BK];    // 16 KB
    __shared__ int   rowtok[BM];
    __shared__ float roww[BM];

    int tid = threadIdx.x;
    if (tid < BM) {
        int slot = m0 + ((tid < mcnt) ? tid : 0);
        rowtok[tid] = perm[slot];
        roww[tid]   = wts[slot];
    }
    __syncthreads();

    int wave = tid >> 6, lane = tid & 63;
    int srow   = wave * 8 + (lane >> 3);
    int schunk = (((lane & 7) ^ ((lane >> 3) & 7))) * 8;   // XOR swizzle on GLOBAL side
    const __bf16* We = Wcat + (size_t)e * (2 * F_DIM) * H_DIM;
    const __bf16* aptr[4];
    const __bf16* bptr[4];
#pragma unroll
    for (int j = 0; j < 4; ++j) {
        int r = j * 32 + srow;
        aptr[j] = xb + (size_t)rowtok[r] * H_DIM + schunk;
        bptr[j] = We + (size_t)(n0 + r) * H_DIM + schunk;
    }
    __bf16* aLds = As + wave * 512;
    __bf16* bLds = Bs + wave * 512;

    int wm = wave & 1, wn = wave >> 1;
    int quad = lane >> 4, l16 = lane & 15;

    f32x4 acc[4][4];
#pragma unroll
    for (int a = 0; a < 4; ++a)
#pragma unroll
        for (int b = 0; b < 4; ++b) acc[a][b] = (f32x4){0.f, 0.f, 0.f, 0.f};

    for (int k0 = 0; k0 < H_DIM; k0 += BK) {
#pragma unroll
        for (int j = 0; j < 4; ++j) {
            gl_lds16(aptr[j] + k0, aLds + j * 2048);
            gl_lds16(bptr[j] + k0, bLds + j * 2048);
        }
        __syncthreads();
#pragma unroll
        for (int s = 0; s < 2; ++s) {
            int sw = (((quad + s * 4) ^ (l16 & 7))) * 8;
            bf16x8 af[4], bf[4];
#pragma unroll
            for (int im = 0; im < 4; ++im)
                af[im] = *(const bf16x8*)&As[(wm * 64 + im * 16 + l16) * 64 + sw];
#pragma unroll
            for (int in = 0; in < 4; ++in)
                bf[in] = *(const bf16x8*)&Bs[(wn * 64 + in * 16 + l16) * 64 + sw];
#pragma unroll
            for (int im = 0; im < 4; ++im)
#pragma unroll
                for (int in = 0; in < 4; ++in)
                    acc[im][in] = MFMA16(af[im], bf[in], acc[im][in]);
        }
        __syncthreads();
    }

    // Epilogue: packed col in even=gate, odd=up (same f). f = n0/2 + wn*32 + (in>>1)*16 + l16.
    int fbase = (n0 >> 1) + wn * 32;
#pragma unroll
    for (int im = 0; im < 4; ++im) {
#pragma unroll
        for (int ip = 0; ip < 2; ++ip) {
            f32x4 g = acc[im][ip * 2], u = acc[im][ip * 2 + 1];
            int fcol = fbase + ip * 16 + l16;
#pragma unroll
            for (int r = 0; r < 4; ++r) {
                int rl = wm * 64 + im * 16 + quad * 4 + r;
                if (rl < mcnt) {
                    float gv = g[r], uv = u[r];
                    float sg = gv / (1.f + __expf(-gv));
                    act[(size_t)(m0 + rl) * F_DIM + fcol] = (__bf16)(sg * uv * roww[rl]);
                }
            }
        }
    }
}

// ---------------------------------------------------------------------------
// m97-structure grouped down-proj: out[token][h] += act_slot @ Wd[e].
// Same staging/swizzle/grid-decode; epilogue fp32 atomics (<=2 writers/addr).
// ---------------------------------------------------------------------------
__global__ __launch_bounds__(256, 3) void down_kernel(
    const __bf16* __restrict__ act, const __bf16* __restrict__ Wdt,
    const int* __restrict__ perm,
    const int* __restrict__ tile_e, const int* __restrict__ tile_m0, const int* __restrict__ tile_cnt,
    const int* __restrict__ n_tiles, float* __restrict__ out)
{
    int mt = blockIdx.x >> 3;
    if (mt >= *n_tiles) return;
    int e = tile_e[mt], m0 = tile_m0[mt], mcnt = tile_cnt[mt];
    int n0 = (blockIdx.x & 7) * BN;

    __shared__ __align__(16) __bf16 As[BM * BK];
    __shared__ __align__(16) __bf16 Bs[BN * BK];
    __shared__ int rowtok[BM];

    int tid = threadIdx.x;
    if (tid < BM) rowtok[tid] = perm[m0 + ((tid < mcnt) ? tid : 0)];
    __syncthreads();

    int wave = tid >> 6, lane = tid & 63;
    int srow   = wave * 8 + (lane >> 3);
    int schunk = (((lane & 7) ^ ((lane >> 3) & 7))) * 8;
    const __bf16* Wd_e = Wdt + (size_t)e * H_DIM * F_DIM;
    const __bf16* aptr[4];
    const __bf16* bptr[4];
#pragma unroll
    for (int j = 0; j < 4; ++j) {
        int r = j * 32 + srow;
        int ar = m0 + ((r < mcnt) ? r : 0);
        aptr[j] = act  + (size_t)ar * F_DIM + schunk;
        bptr[j] = Wd_e + (size_t)(n0 + r) * F_DIM + schunk;
    }
    __bf16* aLds = As + wave * 512;
    __bf16* bLds = Bs + wave * 512;

    int wm = wave & 1, wn = wave >> 1;
    int quad = lane >> 4, l16 = lane & 15;

    f32x4 acc[4][4];
#pragma unroll
    for (int a = 0; a < 4; ++a)
#pragma unroll
        for (int b = 0; b < 4; ++b) acc[a][b] = (f32x4){0.f, 0.f, 0.f, 0.f};

    for (int k0 = 0; k0 < F_DIM; k0 += BK) {
#pragma unroll
        for (int j = 0; j < 4; ++j) {
            gl_lds16(aptr[j] + k0, aLds + j * 2048);
            gl_lds16(bptr[j] + k0, bLds + j * 2048);
        }
        __syncthreads();
#pragma unroll
        for (int s = 0; s < 2; ++s) {
            int sw = (((quad + s * 4) ^ (l16 & 7))) * 8;
            bf16x8 af[4], bf[4];
#pragma unroll
            for (int im = 0; im < 4; ++im)
                af[im] = *(const bf16x8*)&As[(wm * 64 + im * 16 + l16) * 64 + sw];
#pragma unroll
            for (int in = 0; in < 4; ++in)
                bf[in] = *(const bf16x8*)&Bs[(wn * 64 + in * 16 + l16) * 64 + sw];
#pragma unroll
            for (int im = 0; im < 4; ++im)
#pragma unroll
                for (int in = 0; in < 4; ++in)
                    acc[im][in] = MFMA16(af[im], bf[in], acc[im][in]);
        }
        __syncthreads();
    }

#pragma unroll
    for (int im = 0; im < 4; ++im) {
#pragma unroll
        for (int in = 0; in < 4; ++in) {
            int col = n0 + wn * 64 + in * 16 + l16;
#pragma unroll
            for (int r = 0; r < 4; ++r) {
                int rl = wm * 64 + im * 16 + quad * 4 + r;
                if (rl < mcnt)
                    unsafeAtomicAdd(out + (size_t)rowtok[rl] * H_DIM + col, acc[im][in][r]);
            }
        }
    }
}

// ---------------------------------------------------------------------------
extern "C" void kernel_launch(void* const* d_in, const int* in_sizes, int n_in,
                              void* d_out, int out_size, void* d_ws, size_t ws_size,
                              hipStream_t stream)
{
    const float* x  = (const float*)d_in[0];
    const float* Wr = (const float*)d_in[1];
    const float* Wg = (const float*)d_in[2];
    const float* Wu = (const float*)d_in[3];
    const float* Wd = (const float*)d_in[4];
    float* out = (float*)d_out;

    char* ws = (char*)d_ws;
    size_t off = 0;
    auto carve = [&](size_t bytes) {
        char* p = ws + off;
        off = (off + bytes + 255) & ~(size_t)255;
        return p;
    };
    __bf16* xb   = (__bf16*)carve((size_t)T_TOK * H_DIM * 2);                 // 8 MB
    __bf16* Wcat = (__bf16*)carve((size_t)N_EXP * 2 * F_DIM * H_DIM * 2);     // 16 MB
    __bf16* Wdt  = (__bf16*)carve((size_t)N_EXP * H_DIM * F_DIM * 2);         // 8 MB
    __bf16* act  = (__bf16*)carve((size_t)N_ASSIGN * F_DIM * 2);              // 8 MB
    int*   top_e = (int*)carve((size_t)T_TOK * 2 * sizeof(int));
    float* top_w = (float*)carve((size_t)T_TOK * 2 * sizeof(float));
    int*   perm  = (int*)carve((size_t)N_ASSIGN * sizeof(int));
    float* wts   = (float*)carve((size_t)N_ASSIGN * sizeof(float));
    int*   tbase = (int*)carve((size_t)N_EXP * 256 * sizeof(int));
    int*   tl_e  = (int*)carve(MAX_TILES * sizeof(int));
    int*   tl_m0 = (int*)carve(MAX_TILES * sizeof(int));
    int*   tl_cn = (int*)carve(MAX_TILES * sizeof(int));
    int*   n_til = (int*)carve(sizeof(int));

    hipMemsetAsync(d_out, 0, (size_t)out_size * sizeof(float), stream);

    routing_kernel<<<T_TOK / 4, 256, 0, stream>>>(x, Wr, xb, top_e, top_w);
    scan_kernel<<<1, 256, 0, stream>>>(top_e, tl_e, tl_m0, tl_cn, n_til, tbase);
    scatter_kernel<<<N_EXP, 256, 0, stream>>>(top_e, top_w, tbase, perm, wts);
    transpose_kernel<<<dim3(32, 16, 24), 256, 0, stream>>>(Wg, Wu, Wd, Wcat, Wdt);
    gateup_kernel<<<GRID_MT * 8, 256, 0, stream>>>(
        xb, Wcat, perm, wts, tl_e, tl_m0, tl_cn, n_til, act);
    down_kernel<<<GRID_MT * 8, 256, 0, stream>>>(
        act, Wdt, perm, tl_e, tl_m0, tl_cn, n_til, out);
}

// Round 6
// 206.121 us; speedup vs baseline: 1.1469x; 1.0732x over previous
//
#include <hip/hip_runtime.h>
#include <hip/hip_bf16.h>

// Problem constants (B=2,S=2048 -> T=4096 tokens), H=1024, F=512, E=8, top-2.
#define T_TOK    4096
#define H_DIM    1024
#define F_DIM    512
#define N_EXP    8
#define N_ASSIGN 8192          // T_TOK * 2
#define BM 128
#define BN 128
#define BK 64
#define MAX_TILES 80
#define GRID_MT   71           // worst-case sum_e ceil(Ne/128) = 64 + 7

typedef __bf16 bf16x8 __attribute__((ext_vector_type(8)));
typedef __bf16 bf16x2 __attribute__((ext_vector_type(2)));
typedef float  f32x4  __attribute__((ext_vector_type(4)));

#define MFMA16(a, b, c) __builtin_amdgcn_mfma_f32_16x16x32_bf16((a), (b), (c), 0, 0, 0)

// Async global->LDS, 16B per lane. LDS dest = wave-uniform base + lane*16.
__device__ __forceinline__ void gl_lds16(const __bf16* g, __bf16* l) {
    __builtin_amdgcn_global_load_lds(
        (const __attribute__((address_space(1))) unsigned int*)g,
        (__attribute__((address_space(3))) unsigned int*)l,
        16, 0, 0);
}

// ---------------------------------------------------------------------------
// Routing: 1 wave = 1 token. Fuses x fp32->bf16 conversion. No global atomics
// (R2: clustered atomicAdds serialized 100us at the TCC).
// ---------------------------------------------------------------------------
__global__ __launch_bounds__(256) void routing_kernel(
    const float* __restrict__ x, const float* __restrict__ Wr,
    __bf16* __restrict__ xb, int* __restrict__ top_e, float* __restrict__ top_w)
{
    int wave = threadIdx.x >> 6, lane = threadIdx.x & 63;
    int t = blockIdx.x * 4 + wave;
    const float* xrow = x + (size_t)t * H_DIM;
    __bf16* xbrow = xb + (size_t)t * H_DIM;

    float part[N_EXP];
#pragma unroll
    for (int e = 0; e < N_EXP; ++e) part[e] = 0.f;

#pragma unroll
    for (int half = 0; half < 2; ++half) {
        int h0 = half * 512 + lane * 8;
        float4 v0 = *(const float4*)(xrow + h0);
        float4 v1 = *(const float4*)(xrow + h0 + 4);
        float xs[8] = {v0.x, v0.y, v0.z, v0.w, v1.x, v1.y, v1.z, v1.w};
        bf16x8 bv;
#pragma unroll
        for (int i = 0; i < 8; ++i) bv[i] = (__bf16)xs[i];
        *(bf16x8*)(xbrow + h0) = bv;
#pragma unroll
        for (int i = 0; i < 8; ++i) {
            const float4* wr = (const float4*)(Wr + (size_t)(h0 + i) * N_EXP);
            float4 w0 = wr[0], w1 = wr[1];
            part[0] += xs[i] * w0.x; part[1] += xs[i] * w0.y;
            part[2] += xs[i] * w0.z; part[3] += xs[i] * w0.w;
            part[4] += xs[i] * w1.x; part[5] += xs[i] * w1.y;
            part[6] += xs[i] * w1.z; part[7] += xs[i] * w1.w;
        }
    }
#pragma unroll
    for (int m = 1; m < 64; m <<= 1) {
#pragma unroll
        for (int e = 0; e < N_EXP; ++e) part[e] += __shfl_xor(part[e], m, 64);
    }
    if (lane == 0) {
        float v1 = -1e30f, v2 = -1e30f;
        int i1 = 0, i2 = 0;
#pragma unroll
        for (int e = 0; e < N_EXP; ++e) {
            float p = part[e];
            if (p > v1)      { v2 = v1; i2 = i1; v1 = p; i1 = e; }
            else if (p > v2) { v2 = p;  i2 = e; }
        }
        float w1 = 1.f / (1.f + __expf(v2 - v1));
        top_e[t * 2]     = i1;  top_e[t * 2 + 1] = i2;
        top_w[t * 2]     = w1;  top_w[t * 2 + 1] = 1.f - w1;
    }
}

// ---------------------------------------------------------------------------
// Scan kernel (1 block): histogram + Hillis-Steele scan -> tile worklist +
// per-(thread,expert) scatter bases.
// ---------------------------------------------------------------------------
__global__ __launch_bounds__(256) void scan_kernel(
    const int* __restrict__ top_e,
    int* __restrict__ tile_e, int* __restrict__ tile_m0, int* __restrict__ tile_cnt,
    int* __restrict__ n_tiles, int* __restrict__ tbase)   // tbase[8][256]
{
    __shared__ int hist[N_EXP][256];
    __shared__ int ebase[N_EXP];
    int tid = threadIdx.x;

    int c[N_EXP];
#pragma unroll
    for (int e = 0; e < N_EXP; ++e) c[e] = 0;
#pragma unroll 4
    for (int i = 0; i < 32; ++i) {
        int ee = top_e[tid * 32 + i];
#pragma unroll
        for (int e = 0; e < N_EXP; ++e) c[e] += (ee == e);
    }
#pragma unroll
    for (int e = 0; e < N_EXP; ++e) hist[e][tid] = c[e];
    __syncthreads();

    for (int s = 1; s < 256; s <<= 1) {
        int v[N_EXP];
#pragma unroll
        for (int e = 0; e < N_EXP; ++e) v[e] = (tid >= s) ? hist[e][tid - s] : 0;
        __syncthreads();
#pragma unroll
        for (int e = 0; e < N_EXP; ++e) hist[e][tid] += v[e];
        __syncthreads();
    }

    if (tid == 0) {
        int o = 0, nt = 0;
        for (int e = 0; e < N_EXP; ++e) {
            ebase[e] = o;
            int ne = hist[e][255];
            for (int m0 = 0; m0 < ne; m0 += BM) {
                tile_e[nt]   = e;
                tile_m0[nt]  = o + m0;
                tile_cnt[nt] = (ne - m0 < BM) ? (ne - m0) : BM;
                ++nt;
            }
            o += ne;
        }
        *n_tiles = nt;
    }
    __syncthreads();

#pragma unroll
    for (int e = 0; e < N_EXP; ++e)
        tbase[e * 256 + tid] = ebase[e] + hist[e][tid] - c[e];
}

// ---------------------------------------------------------------------------
// Scatter kernel: one block per expert; deterministic, no atomics. Also
// records the inverse map tokslot[a] = slot for the combine kernel.
// ---------------------------------------------------------------------------
__global__ __launch_bounds__(256) void scatter_kernel(
    const int* __restrict__ top_e, const float* __restrict__ top_w,
    const int* __restrict__ tbase,
    int* __restrict__ perm, float* __restrict__ wts, int* __restrict__ tokslot)
{
    int e = blockIdx.x, tid = threadIdx.x;
    int base = tbase[e * 256 + tid];
#pragma unroll 4
    for (int i = 0; i < 32; ++i) {
        int a = tid * 32 + i;
        if (top_e[a] == e) {
            perm[base]   = a >> 1;
            wts[base]    = top_w[a];
            tokslot[a]   = base;
            ++base;
        }
    }
}

// ---------------------------------------------------------------------------
// fp32 -> bf16 + transpose to K(=src row)-contiguous layouts.
//   z<8 : Wg[h][f] -> Wcat[e][p_g(f)][h]    p_g(f) = (f>>4)*32 + (f&15)
//   z<16: Wu[h][f] -> Wcat[e][p_u(f)][h]    p_u(f) = p_g(f) + 16
//   else: Wd[f][h] -> Wdt [e][h][f]
// ---------------------------------------------------------------------------
__global__ __launch_bounds__(256) void transpose_kernel(
    const float* __restrict__ Wg, const float* __restrict__ Wu, const float* __restrict__ Wd,
    __bf16* __restrict__ Wcat, __bf16* __restrict__ Wdt)
{
    int z = blockIdx.z;
    const float* src; int R, C;
    if (z < 8)       { src = Wg + (size_t)z * H_DIM * F_DIM;        R = H_DIM; C = F_DIM; }
    else if (z < 16) { src = Wu + (size_t)(z - 8) * H_DIM * F_DIM;  R = H_DIM; C = F_DIM; }
    else             { src = Wd + (size_t)(z - 16) * F_DIM * H_DIM; R = F_DIM; C = H_DIM; }
    int c0 = blockIdx.x * 32, r0 = blockIdx.y * 64;
    if (c0 >= C || r0 >= R) return;
    __shared__ float tile[64][33];
    int tx = threadIdx.x & 31, ty = threadIdx.x >> 5;    // 32 x 8
#pragma unroll
    for (int i = 0; i < 8; ++i)
        tile[ty + 8 * i][tx] = src[(size_t)(r0 + ty + 8 * i) * C + c0 + tx];
    __syncthreads();
    if (z < 16) {
        int e = (z < 8) ? z : z - 8;
        int sel = (z < 8) ? 0 : 16;
        __bf16* dst = Wcat + (size_t)e * (2 * F_DIM) * H_DIM;
#pragma unroll
        for (int i = 0; i < 4; ++i) {
            int f = c0 + ty + 8 * i;
            int p = ((f >> 4) << 5) + (f & 15) + sel;
            bf16x2 v = { (__bf16)tile[2 * tx][ty + 8 * i], (__bf16)tile[2 * tx + 1][ty + 8 * i] };
            *(bf16x2*)&dst[(size_t)p * H_DIM + r0 + 2 * tx] = v;
        }
    } else {
        __bf16* dst = Wdt + (size_t)(z - 16) * H_DIM * F_DIM;
#pragma unroll
        for (int i = 0; i < 4; ++i) {
            bf16x2 v = { (__bf16)tile[2 * tx][ty + 8 * i], (__bf16)tile[2 * tx + 1][ty + 8 * i] };
            *(bf16x2*)&dst[(size_t)(c0 + ty + 8 * i) * F_DIM + r0 + 2 * tx] = v;
        }
    }
}

// ---------------------------------------------------------------------------
// m97-structure grouped GEMM for gate+up (packed N=1024), 128x128 tile, BK=64,
// global_load_lds width-16 staging, XOR-swizzled LDS. 1-D grid, n-fastest
// decode (A-tile L3 reuse adjacent; B-tile + XCD affinity at stride 8).
// Epilogue: silu(gate)*up*combine_weight -> act (bf16).
// ---------------------------------------------------------------------------
__global__ __launch_bounds__(256, 3) void gateup_kernel(
    const __bf16* __restrict__ xb, const __bf16* __restrict__ Wcat,
    const int* __restrict__ perm, const float* __restrict__ wts,
    const int* __restrict__ tile_e, const int* __restrict__ tile_m0, const int* __restrict__ tile_cnt,
    const int* __restrict__ n_tiles, __bf16* __restrict__ act)
{
    int mt = blockIdx.x >> 3;               // n varies fastest
    if (mt >= *n_tiles) return;
    int e = tile_e[mt], m0 = tile_m0[mt], mcnt = tile_cnt[mt];
    int n0 = (blockIdx.x & 7) * BN;         // packed col base

    __shared__ __align__(16) __bf16 As[BM * BK];    // 16 KB
    __shared__ __align__(16) __bf16 Bs[BN * BK];    // 16 KB
    __shared__ int   rowtok[BM];
    __shared__ float roww[BM];

    int tid = threadIdx.x;
    if (tid < BM) {
        int slot = m0 + ((tid < mcnt) ? tid : 0);
        rowtok[tid] = perm[slot];
        roww[tid]   = wts[slot];
    }
    __syncthreads();

    int wave = tid >> 6, lane = tid & 63;
    int srow   = wave * 8 + (lane >> 3);
    int schunk = (((lane & 7) ^ ((lane >> 3) & 7))) * 8;   // XOR swizzle on GLOBAL side
    const __bf16* We = Wcat + (size_t)e * (2 * F_DIM) * H_DIM;
    const __bf16* aptr[4];
    const __bf16* bptr[4];
#pragma unroll
    for (int j = 0; j < 4; ++j) {
        int r = j * 32 + srow;
        aptr[j] = xb + (size_t)rowtok[r] * H_DIM + schunk;
        bptr[j] = We + (size_t)(n0 + r) * H_DIM + schunk;
    }
    __bf16* aLds = As + wave * 512;
    __bf16* bLds = Bs + wave * 512;

    int wm = wave & 1, wn = wave >> 1;
    int quad = lane >> 4, l16 = lane & 15;

    f32x4 acc[4][4];
#pragma unroll
    for (int a = 0; a < 4; ++a)
#pragma unroll
        for (int b = 0; b < 4; ++b) acc[a][b] = (f32x4){0.f, 0.f, 0.f, 0.f};

    for (int k0 = 0; k0 < H_DIM; k0 += BK) {
#pragma unroll
        for (int j = 0; j < 4; ++j) {
            gl_lds16(aptr[j] + k0, aLds + j * 2048);
            gl_lds16(bptr[j] + k0, bLds + j * 2048);
        }
        __syncthreads();
#pragma unroll
        for (int s = 0; s < 2; ++s) {
            int sw = (((quad + s * 4) ^ (l16 & 7))) * 8;
            bf16x8 af[4], bf[4];
#pragma unroll
            for (int im = 0; im < 4; ++im)
                af[im] = *(const bf16x8*)&As[(wm * 64 + im * 16 + l16) * 64 + sw];
#pragma unroll
            for (int in = 0; in < 4; ++in)
                bf[in] = *(const bf16x8*)&Bs[(wn * 64 + in * 16 + l16) * 64 + sw];
#pragma unroll
            for (int im = 0; im < 4; ++im)
#pragma unroll
                for (int in = 0; in < 4; ++in)
                    acc[im][in] = MFMA16(af[im], bf[in], acc[im][in]);
        }
        __syncthreads();
    }

    // Epilogue: packed col in even=gate, odd=up (same f). f = n0/2 + wn*32 + (in>>1)*16 + l16.
    int fbase = (n0 >> 1) + wn * 32;
#pragma unroll
    for (int im = 0; im < 4; ++im) {
#pragma unroll
        for (int ip = 0; ip < 2; ++ip) {
            f32x4 g = acc[im][ip * 2], u = acc[im][ip * 2 + 1];
            int fcol = fbase + ip * 16 + l16;
#pragma unroll
            for (int r = 0; r < 4; ++r) {
                int rl = wm * 64 + im * 16 + quad * 4 + r;
                if (rl < mcnt) {
                    float gv = g[r], uv = u[r];
                    float sg = gv / (1.f + __expf(-gv));
                    act[(size_t)(m0 + rl) * F_DIM + fcol] = (__bf16)(sg * uv * roww[rl]);
                }
            }
        }
    }
}

// ---------------------------------------------------------------------------
// m97-structure grouped down-proj: P[slot][h] = act[slot] @ Wd[e]  (plain
// fp32 stores -- R5 post-mortem: the 8.4M fp32 atomic RMWs serialized at the
// TCC were the 42us; each P row is written exactly once, combine adds pairs).
// ---------------------------------------------------------------------------
__global__ __launch_bounds__(256, 3) void down_kernel(
    const __bf16* __restrict__ act, const __bf16* __restrict__ Wdt,
    const int* __restrict__ tile_e, const int* __restrict__ tile_m0, const int* __restrict__ tile_cnt,
    const int* __restrict__ n_tiles, float* __restrict__ P)
{
    int mt = blockIdx.x >> 3;
    if (mt >= *n_tiles) return;
    int e = tile_e[mt], m0 = tile_m0[mt], mcnt = tile_cnt[mt];
    int n0 = (blockIdx.x & 7) * BN;

    __shared__ __align__(16) __bf16 As[BM * BK];
    __shared__ __align__(16) __bf16 Bs[BN * BK];

    int tid = threadIdx.x;
    int wave = tid >> 6, lane = tid & 63;
    int srow   = wave * 8 + (lane >> 3);
    int schunk = (((lane & 7) ^ ((lane >> 3) & 7))) * 8;
    const __bf16* Wd_e = Wdt + (size_t)e * H_DIM * F_DIM;
    const __bf16* aptr[4];
    const __bf16* bptr[4];
#pragma unroll
    for (int j = 0; j < 4; ++j) {
        int r = j * 32 + srow;
        int ar = m0 + ((r < mcnt) ? r : 0);
        aptr[j] = act  + (size_t)ar * F_DIM + schunk;
        bptr[j] = Wd_e + (size_t)(n0 + r) * F_DIM + schunk;
    }
    __bf16* aLds = As + wave * 512;
    __bf16* bLds = Bs + wave * 512;

    int wm = wave & 1, wn = wave >> 1;
    int quad = lane >> 4, l16 = lane & 15;

    f32x4 acc[4][4];
#pragma unroll
    for (int a = 0; a < 4; ++a)
#pragma unroll
        for (int b = 0; b < 4; ++b) acc[a][b] = (f32x4){0.f, 0.f, 0.f, 0.f};

    for (int k0 = 0; k0 < F_DIM; k0 += BK) {
#pragma unroll
        for (int j = 0; j < 4; ++j) {
            gl_lds16(aptr[j] + k0, aLds + j * 2048);
            gl_lds16(bptr[j] + k0, bLds + j * 2048);
        }
        __syncthreads();
#pragma unroll
        for (int s = 0; s < 2; ++s) {
            int sw = (((quad + s * 4) ^ (l16 & 7))) * 8;
            bf16x8 af[4], bf[4];
#pragma unroll
            for (int im = 0; im < 4; ++im)
                af[im] = *(const bf16x8*)&As[(wm * 64 + im * 16 + l16) * 64 + sw];
#pragma unroll
            for (int in = 0; in < 4; ++in)
                bf[in] = *(const bf16x8*)&Bs[(wn * 64 + in * 16 + l16) * 64 + sw];
#pragma unroll
            for (int im = 0; im < 4; ++im)
#pragma unroll
                for (int in = 0; in < 4; ++in)
                    acc[im][in] = MFMA16(af[im], bf[in], acc[im][in]);
        }
        __syncthreads();
    }

#pragma unroll
    for (int im = 0; im < 4; ++im) {
#pragma unroll
        for (int in = 0; in < 4; ++in) {
            int col = n0 + wn * 64 + in * 16 + l16;
#pragma unroll
            for (int r = 0; r < 4; ++r) {
                int rl = wm * 64 + im * 16 + quad * 4 + r;
                if (rl < mcnt)
                    P[(size_t)(m0 + rl) * H_DIM + col] = acc[im][in][r];
            }
        }
    }
}

// ---------------------------------------------------------------------------
// Combine: out[t] = P[slot1(t)] + P[slot2(t)]. 1 wave/token, float4 I/O.
// P is L3-resident (32 MB). Fully overwrites out (no memset needed).
// ---------------------------------------------------------------------------
__global__ __launch_bounds__(256) void combine_kernel(
    const float* __restrict__ P, const int* __restrict__ tokslot,
    float* __restrict__ out)
{
    int wave = threadIdx.x >> 6, lane = threadIdx.x & 63;
    int t = blockIdx.x * 4 + wave;
    int s1 = tokslot[2 * t], s2 = tokslot[2 * t + 1];
    const f32x4* p1 = (const f32x4*)(P + (size_t)s1 * H_DIM);
    const f32x4* p2 = (const f32x4*)(P + (size_t)s2 * H_DIM);
    f32x4* o = (f32x4*)(out + (size_t)t * H_DIM);
#pragma unroll
    for (int i = 0; i < H_DIM / 4 / 64; ++i) {
        int idx = i * 64 + lane;
        f32x4 a = p1[idx], b = p2[idx];
        o[idx] = (f32x4){a.x + b.x, a.y + b.y, a.z + b.z, a.w + b.w};
    }
}

// ---------------------------------------------------------------------------
extern "C" void kernel_launch(void* const* d_in, const int* in_sizes, int n_in,
                              void* d_out, int out_size, void* d_ws, size_t ws_size,
                              hipStream_t stream)
{
    const float* x  = (const float*)d_in[0];
    const float* Wr = (const float*)d_in[1];
    const float* Wg = (const float*)d_in[2];
    const float* Wu = (const float*)d_in[3];
    const float* Wd = (const float*)d_in[4];
    float* out = (float*)d_out;

    char* ws = (char*)d_ws;
    size_t off = 0;
    auto carve = [&](size_t bytes) {
        char* p = ws + off;
        off = (off + bytes + 255) & ~(size_t)255;
        return p;
    };
    __bf16* xb   = (__bf16*)carve((size_t)T_TOK * H_DIM * 2);                 // 8 MB
    __bf16* Wcat = (__bf16*)carve((size_t)N_EXP * 2 * F_DIM * H_DIM * 2);     // 16 MB
    __bf16* Wdt  = (__bf16*)carve((size_t)N_EXP * H_DIM * F_DIM * 2);         // 8 MB
    __bf16* act  = (__bf16*)carve((size_t)N_ASSIGN * F_DIM * 2);              // 8 MB
    float* P     = (float*)carve((size_t)N_ASSIGN * H_DIM * sizeof(float));   // 32 MB
    int*   top_e = (int*)carve((size_t)T_TOK * 2 * sizeof(int));
    float* top_w = (float*)carve((size_t)T_TOK * 2 * sizeof(float));
    int*   perm  = (int*)carve((size_t)N_ASSIGN * sizeof(int));
    float* wts   = (float*)carve((size_t)N_ASSIGN * sizeof(float));
    int*  tokslot= (int*)carve((size_t)N_ASSIGN * sizeof(int));
    int*   tbase = (int*)carve((size_t)N_EXP * 256 * sizeof(int));
    int*   tl_e  = (int*)carve(MAX_TILES * sizeof(int));
    int*   tl_m0 = (int*)carve(MAX_TILES * sizeof(int));
    int*   tl_cn = (int*)carve(MAX_TILES * sizeof(int));
    int*   n_til = (int*)carve(sizeof(int));

    routing_kernel<<<T_TOK / 4, 256, 0, stream>>>(x, Wr, xb, top_e, top_w);
    scan_kernel<<<1, 256, 0, stream>>>(top_e, tl_e, tl_m0, tl_cn, n_til, tbase);
    scatter_kernel<<<N_EXP, 256, 0, stream>>>(top_e, top_w, tbase, perm, wts, tokslot);
    transpose_kernel<<<dim3(32, 16, 24), 256, 0, stream>>>(Wg, Wu, Wd, Wcat, Wdt);
    gateup_kernel<<<GRID_MT * 8, 256, 0, stream>>>(
        xb, Wcat, perm, wts, tl_e, tl_m0, tl_cn, n_til, act);
    down_kernel<<<GRID_MT * 8, 256, 0, stream>>>(
        act, Wdt, tl_e, tl_m0, tl_cn, n_til, P);
    combine_kernel<<<T_TOK / 4, 256, 0, stream>>>(P, tokslot, out);
}